// Round 1
// baseline (399.963 us; speedup 1.0000x reference)
//
#include <hip/hip_runtime.h>
#include <math.h>

#define NB 2
#define LSEQ 2048
#define DM 512
#define MM 64
#define CHK 64
#define NCHUNK 32

__device__ __forceinline__ float get_ld(const float* __restrict__ logit) {
    float lg = *logit;
    float dec = 1.0f / (1.0f + expf(-lg));
    dec = fmaxf(dec, 1e-6f);
    return logf(dec);
}
__device__ __forceinline__ float cpos(float ld, int t) {
    return fminf(fmaxf(ld * (float)t, -20.0f), 20.0f);
}
__device__ __forceinline__ float phi_fn(float v) {
    return v > 0.0f ? v + 1.0f : expf(v);
}

// C(rows x ncols) = X(rows x kd) @ W(ncols x kd)^T ; epi: 0=none, 1=phi(.)*scale
__global__ __launch_bounds__(256) void gemm_bt(
    const float* __restrict__ X, const float* __restrict__ W,
    float* __restrict__ C, int ncols, int kd, int epi, float scale)
{
    __shared__ float Xs[64][33];
    __shared__ float Ws[64][33];
    const int brow = blockIdx.x * 64;
    const int bcol = blockIdx.y * 64;
    const int tid = threadIdx.x;
    const int tx = tid & 15, ty = tid >> 4;
    float acc[4][4];
#pragma unroll
    for (int i = 0; i < 4; ++i)
#pragma unroll
        for (int j = 0; j < 4; ++j) acc[i][j] = 0.f;

    for (int k0 = 0; k0 < kd; k0 += 32) {
#pragma unroll
        for (int l = 0; l < 8; ++l) {
            int e = tid + l * 256;
            int r = e >> 5, kk = e & 31;
            Xs[r][kk] = X[(size_t)(brow + r) * kd + k0 + kk];
            Ws[r][kk] = W[(size_t)(bcol + r) * kd + k0 + kk];
        }
        __syncthreads();
#pragma unroll
        for (int kk = 0; kk < 32; ++kk) {
            float xv[4], wv[4];
#pragma unroll
            for (int i = 0; i < 4; ++i) xv[i] = Xs[ty * 4 + i][kk];
#pragma unroll
            for (int j = 0; j < 4; ++j) wv[j] = Ws[tx * 4 + j][kk];
#pragma unroll
            for (int i = 0; i < 4; ++i)
#pragma unroll
                for (int j = 0; j < 4; ++j) acc[i][j] += xv[i] * wv[j];
        }
        __syncthreads();
    }
#pragma unroll
    for (int i = 0; i < 4; ++i)
#pragma unroll
        for (int j = 0; j < 4; ++j) {
            float v = acc[i][j];
            if (epi) v = phi_fn(v) * scale;
            C[(size_t)(brow + ty * 4 + i) * ncols + bcol + tx * 4 + j] = v;
        }
}

// Per (chunk, dgroup, batch): intra-chunk attention + chunk summaries.
__global__ __launch_bounds__(256) void chunk_local(
    const float* __restrict__ Q, const float* __restrict__ Kmat,
    const float* __restrict__ V, const float* __restrict__ logit,
    float* __restrict__ OI, float* __restrict__ DI,
    float* __restrict__ KV, float* __restrict__ KZ)
{
    const int chunk = blockIdx.x;   // 0..31
    const int dg = blockIdx.y;      // 0..3 (128 cols each)
    const int b = blockIdx.z;       // 0..1
    const int tid = threadIdx.x;
    const int t0 = chunk * CHK;
    const float ld = get_ld(logit);

    __shared__ float Qs[CHK][MM + 1];
    __shared__ float Ks[CHK][MM + 1];
    __shared__ float As[CHK][CHK + 1];
    __shared__ float Vt[16][128];
    __shared__ float wk[CHK];

    const float* Qb = Q + ((size_t)b * LSEQ + t0) * MM;
    const float* Kb = Kmat + ((size_t)b * LSEQ + t0) * MM;
#pragma unroll
    for (int l = 0; l < 16; ++l) {
        int e = tid + l * 256;
        int r = e >> 6, m = e & 63;
        Qs[r][m] = Qb[e];
        Ks[r][m] = Kb[e];
    }
    if (tid < CHK) {
        wk[tid] = expf(cpos(ld, t0 + CHK - 1) - cpos(ld, t0 + tid));
    }
    __syncthreads();

    // A[t][s] = (q_t . k_s) * exp(c_t - c_s) for s<=t else 0
    {
        const int t = tid >> 2, j = tid & 3;
        const float ct = cpos(ld, t0 + t);
#pragma unroll
        for (int ii = 0; ii < 16; ++ii) {
            int s = j + ii * 4;
            float a = 0.f;
            if (s <= t) {
#pragma unroll
                for (int m = 0; m < MM; ++m) a += Qs[t][m] * Ks[s][m];
                a *= expf(ct - cpos(ld, t0 + s));
            }
            As[t][s] = a;
        }
    }
    __syncthreads();

    if (dg == 0 && tid < CHK) {
        float sden = 0.f;
#pragma unroll
        for (int s = 0; s < CHK; ++s) sden += As[tid][s];
        DI[(size_t)b * LSEQ + t0 + tid] = sden;
        float skz = 0.f;
#pragma unroll
        for (int s = 0; s < CHK; ++s) skz += wk[s] * Ks[s][tid];
        KZ[((size_t)b * NCHUNK + chunk) * MM + tid] = skz;
    }

    // O_intra and KV for our 128-wide d slice
    const int dcol = tid & 127;
    const int half = tid >> 7;
    const int dglob = dg * 128 + dcol;
    float accO[32], accKV[32];
#pragma unroll
    for (int i = 0; i < 32; ++i) { accO[i] = 0.f; accKV[i] = 0.f; }

    const float* Vb = V + ((size_t)b * LSEQ + t0) * DM + dg * 128;
    for (int s0 = 0; s0 < CHK; s0 += 16) {
        __syncthreads();
#pragma unroll
        for (int l = 0; l < 8; ++l) {
            int e = tid + l * 256;
            int s = e >> 7, dd = e & 127;
            Vt[s][dd] = Vb[(size_t)(s0 + s) * DM + dd];
        }
        __syncthreads();
#pragma unroll
        for (int s = 0; s < 16; ++s) {
            const int sg = s0 + s;
            const float v = Vt[s][dcol];
            const float vw = wk[sg] * v;
#pragma unroll
            for (int t = 0; t < 32; ++t) accO[t] += As[half * 32 + t][sg] * v;
#pragma unroll
            for (int m = 0; m < 32; ++m) accKV[m] += Ks[sg][half * 32 + m] * vw;
        }
    }

    float* OIb = OI + ((size_t)b * LSEQ + t0) * DM;
#pragma unroll
    for (int t = 0; t < 32; ++t)
        OIb[(size_t)(half * 32 + t) * DM + dglob] = accO[t];
    float* KVb = KV + ((size_t)b * NCHUNK + chunk) * MM * DM;
#pragma unroll
    for (int m = 0; m < 32; ++m)
        KVb[(size_t)(half * 32 + m) * DM + dglob] = accKV[m];
}

// Sequential scan over chunks (per element of the 64x512 state, per batch).
__global__ __launch_bounds__(256) void state_scan(
    const float* __restrict__ KV, const float* __restrict__ KZ,
    const float* __restrict__ logit,
    float* __restrict__ SS, float* __restrict__ ZS)
{
    const int g = blockIdx.x * 256 + threadIdx.x;  // 0..65535
    const int b = g >> 15;
    const int rem = g & 32767;
    const int m = rem >> 9;
    const int d = rem & 511;
    const float ld = get_ld(logit);

    float s = 0.f;
    float zs = 0.f;
    const bool doz = (d == 0);
    float cprev = 0.f;
    for (int i = 0; i < NCHUNK; ++i) {
        const float ce = cpos(ld, i * CHK + CHK - 1);
        const float lam = expf(ce - cprev);
        cprev = ce;
        const size_t idx = (((size_t)b * NCHUNK + i) * MM + m) * DM + d;
        SS[idx] = s;
        s = lam * s + KV[idx];
        if (doz) {
            const int zi = (b * NCHUNK + i) * MM + m;
            ZS[zi] = zs;
            zs = lam * zs + KZ[zi];
        }
    }
}

// Combine inter-chunk contribution: NUM = g_t * q_t.S_prev + O_intra (in place on OIN),
// DEN = g_t * q_t.z_prev + den_intra + 1e-6.
__global__ __launch_bounds__(256) void chunk_combine(
    const float* __restrict__ Q, const float* __restrict__ SS,
    const float* __restrict__ ZS, float* OIN,
    const float* __restrict__ DI, const float* __restrict__ logit,
    float* __restrict__ DEN)
{
    const int chunk = blockIdx.x;
    const int b = blockIdx.y;
    const int tid = threadIdx.x;
    const int t0 = chunk * CHK;
    const float ld = get_ld(logit);

    __shared__ float Qs[CHK][MM + 1];
    __shared__ float gv[CHK];

    const float* Qb = Q + ((size_t)b * LSEQ + t0) * MM;
#pragma unroll
    for (int l = 0; l < 16; ++l) {
        int e = tid + l * 256;
        int r = e >> 6, m = e & 63;
        Qs[r][m] = Qb[e];
    }
    const float cprev = (chunk > 0) ? cpos(ld, t0 - 1) : 0.f;
    if (tid < CHK) gv[tid] = expf(cpos(ld, t0 + tid) - cprev);
    __syncthreads();

    if (tid < CHK) {
        const float* zp = ZS + ((size_t)b * NCHUNK + chunk) * MM;
        float a = 0.f;
#pragma unroll
        for (int m = 0; m < MM; ++m) a += Qs[tid][m] * zp[m];
        DEN[(size_t)b * LSEQ + t0 + tid] =
            gv[tid] * a + DI[(size_t)b * LSEQ + t0 + tid] + 1e-6f;
    }
    __syncthreads();

    const float* Sp = SS + ((size_t)b * NCHUNK + chunk) * MM * DM;
    float* OIb = OIN + ((size_t)b * LSEQ + t0) * DM;
    for (int hh = 0; hh < 2; ++hh) {
        const int d = hh * 256 + tid;
        float acc[CHK];
#pragma unroll
        for (int t = 0; t < CHK; ++t) acc[t] = 0.f;
        for (int m = 0; m < MM; ++m) {
            const float v = Sp[(size_t)m * DM + d];
#pragma unroll
            for (int t = 0; t < CHK; ++t) acc[t] += Qs[t][m] * v;
        }
#pragma unroll
        for (int t = 0; t < CHK; ++t) {
            const size_t o = (size_t)t * DM + d;
            OIb[o] = gv[t] * acc[t] + OIb[o];
        }
    }
}

// RMS norm rows: NRM = (num/den) / rms * w
__global__ __launch_bounds__(256) void rms_kernel(
    const float* __restrict__ NUM, const float* __restrict__ DEN,
    const float* __restrict__ w, float* __restrict__ NRM)
{
    const int row = blockIdx.x;
    const int tid = threadIdx.x;
    const float* nr = NUM + (size_t)row * DM;
    const float den = DEN[row];
    const float inv = 1.0f / den;
    const float x0 = nr[tid] * inv;
    const float x1 = nr[tid + 256] * inv;
    float ss = x0 * x0 + x1 * x1;
#pragma unroll
    for (int i = 1; i < 64; i <<= 1) ss += __shfl_xor(ss, i, 64);
    __shared__ float red[4];
    const int lane = tid & 63, wv = tid >> 6;
    if (lane == 0) red[wv] = ss;
    __syncthreads();
    const float tot = red[0] + red[1] + red[2] + red[3];
    const float rms = sqrtf(tot * (1.0f / (float)DM) + 1e-6f);
    const float rinv = 1.0f / rms;
    NRM[(size_t)row * DM + tid] = x0 * rinv * w[tid];
    NRM[(size_t)row * DM + tid + 256] = x1 * rinv * w[tid + 256];
}

extern "C" void kernel_launch(void* const* d_in, const int* in_sizes, int n_in,
                              void* d_out, int out_size, void* d_ws, size_t ws_size,
                              hipStream_t stream) {
    const float* x      = (const float*)d_in[0];
    const float* W_q    = (const float*)d_in[1];
    const float* W_k    = (const float*)d_in[2];
    const float* W_v    = (const float*)d_in[3];
    const float* W_o    = (const float*)d_in[4];
    const float* logit  = (const float*)d_in[5];
    const float* norm_w = (const float*)d_in[6];
    float* out = (float*)d_out;

    const size_t BLM = (size_t)NB * LSEQ * MM;      // 262144
    const size_t BLD = (size_t)NB * LSEQ * DM;      // 2097152
    const size_t BL  = (size_t)NB * LSEQ;           // 4096
    const size_t BNCMD = (size_t)NB * NCHUNK * MM * DM;
    const size_t BNCM  = (size_t)NB * NCHUNK * MM;

    float* ws = (float*)d_ws;
    float* Qp  = ws;
    float* Kp  = Qp + BLM;
    float* Vp  = Kp + BLM;
    float* OIp = Vp + BLD;        // also NUM (in-place)
    float* DIp = OIp + BLD;
    float* KVp = DIp + BL;
    float* KZp = KVp + BNCMD;
    float* SSp = KZp + BNCM;
    float* ZSp = SSp + BNCMD;
    float* DENp = ZSp + BNCM;
    float* NRMp = Vp;             // alias: V dead after chunk_local

    const int rows = NB * LSEQ;   // 4096

    // Projections
    gemm_bt<<<dim3(rows / 64, 1), 256, 0, stream>>>(x, W_q, Qp, MM, DM, 1, 0.125f);
    gemm_bt<<<dim3(rows / 64, 1), 256, 0, stream>>>(x, W_k, Kp, MM, DM, 1, 1.0f);
    gemm_bt<<<dim3(rows / 64, DM / 64), 256, 0, stream>>>(x, W_v, Vp, DM, DM, 0, 1.0f);

    // Intra-chunk attention + chunk summaries
    chunk_local<<<dim3(NCHUNK, 4, NB), 256, 0, stream>>>(Qp, Kp, Vp, logit,
                                                         OIp, DIp, KVp, KZp);
    // Sequential state scan over chunks
    state_scan<<<dim3(256), 256, 0, stream>>>(KVp, KZp, logit, SSp, ZSp);
    // Inter-chunk combine
    chunk_combine<<<dim3(NCHUNK, NB), 256, 0, stream>>>(Qp, SSp, ZSp, OIp, DIp,
                                                        logit, DENp);
    // RMS norm
    rms_kernel<<<dim3(rows), 256, 0, stream>>>(OIp, DENp, norm_w, NRMp);
    // Output projection
    gemm_bt<<<dim3(rows / 64, DM / 64), 256, 0, stream>>>(NRMp, W_o, out, DM, DM, 0, 1.0f);
}

// Round 2
// 143.214 us; speedup vs baseline: 2.7928x; 2.7928x over previous
//
#include <hip/hip_runtime.h>
#include <math.h>

#define NB 2
#define LSEQ 2048
#define DM 512
#define MM 64
#define CHK 64
#define NCHUNK 32

typedef __attribute__((ext_vector_type(8))) short short8v;
typedef __attribute__((ext_vector_type(4))) float f32x4;

__device__ __forceinline__ float get_ld(const float* __restrict__ logit) {
    float lg = *logit;
    float dec = 1.0f / (1.0f + expf(-lg));
    dec = fmaxf(dec, 1e-6f);
    return logf(dec);
}
__device__ __forceinline__ float cpos(float ld, int t) {
    return fminf(fmaxf(ld * (float)t, -20.0f), 20.0f);
}
__device__ __forceinline__ float phi_fn(float v) {
    return v > 0.0f ? v + 1.0f : expf(v);
}
__device__ __forceinline__ unsigned short f2bf(float f) {
    unsigned int u = __float_as_uint(f);
    u += 0x7FFFu + ((u >> 16) & 1u);   // round-to-nearest-even
    return (unsigned short)(u >> 16);
}

// ---- f32 -> bf16 convert (vectorized, n multiple of 1024) ----
__global__ __launch_bounds__(256) void cvt_bf16(
    const float* __restrict__ in, unsigned short* __restrict__ out, int n4)
{
    int i = blockIdx.x * 256 + threadIdx.x;
    if (i < n4) {
        float4 v = ((const float4*)in)[i];
        ushort4 o;
        o.x = f2bf(v.x); o.y = f2bf(v.y); o.z = f2bf(v.z); o.w = f2bf(v.w);
        ((ushort4*)out)[i] = o;
    }
}

// ---- fused Q/K projection: C = phi(x @ W^T) * scale, 64x64 tiles ----
__global__ __launch_bounds__(256) void gemm_qk(
    const float* __restrict__ X, const float* __restrict__ Wq,
    const float* __restrict__ Wk, float* __restrict__ Qo, float* __restrict__ Ko)
{
    const float* W = blockIdx.y ? Wk : Wq;
    float* C = blockIdx.y ? Ko : Qo;
    const float scale = blockIdx.y ? 1.0f : 0.125f;
    __shared__ float Xs[64][33];
    __shared__ float Ws[64][33];
    const int brow = blockIdx.x * 64;
    const int tid = threadIdx.x;
    const int tx = tid & 15, ty = tid >> 4;
    float acc[4][4];
#pragma unroll
    for (int i = 0; i < 4; ++i)
#pragma unroll
        for (int j = 0; j < 4; ++j) acc[i][j] = 0.f;

    for (int k0 = 0; k0 < DM; k0 += 32) {
#pragma unroll
        for (int l = 0; l < 8; ++l) {
            int e = tid + l * 256;
            int r = e >> 5, kk = e & 31;
            Xs[r][kk] = X[(size_t)(brow + r) * DM + k0 + kk];
            Ws[r][kk] = W[(size_t)r * DM + k0 + kk];
        }
        __syncthreads();
#pragma unroll
        for (int kk = 0; kk < 32; ++kk) {
            float xv[4], wv[4];
#pragma unroll
            for (int i = 0; i < 4; ++i) xv[i] = Xs[ty * 4 + i][kk];
#pragma unroll
            for (int j = 0; j < 4; ++j) wv[j] = Ws[tx * 4 + j][kk];
#pragma unroll
            for (int i = 0; i < 4; ++i)
#pragma unroll
                for (int j = 0; j < 4; ++j) acc[i][j] += xv[i] * wv[j];
        }
        __syncthreads();
    }
#pragma unroll
    for (int i = 0; i < 4; ++i)
#pragma unroll
        for (int j = 0; j < 4; ++j) {
            float v = phi_fn(acc[i][j]) * scale;
            C[(size_t)(brow + ty * 4 + i) * MM + tx * 4 + j] = v;
        }
}

// ---- bf16 MFMA GEMM: C(rows x 512) = Xb @ Wb^T, fp32 out ----
// 128x128 block tile, 4 waves (2x2), each wave 64x64 via 4x4 16x16x32 frags
__global__ __launch_bounds__(256) void gemm_mfma_bt(
    const unsigned short* __restrict__ Xb, const unsigned short* __restrict__ Wb,
    float* __restrict__ C)
{
    __shared__ unsigned short As[128][40];  // row stride 80B (16B-aligned)
    __shared__ unsigned short Bs[128][40];
    const int brow = blockIdx.x * 128;
    const int bcol = blockIdx.y * 128;
    const int tid = threadIdx.x;
    const int lane = tid & 63;
    const int wid = tid >> 6;
    const int wr = wid >> 1, wc = wid & 1;

    f32x4 acc[4][4];
#pragma unroll
    for (int i = 0; i < 4; ++i)
#pragma unroll
        for (int j = 0; j < 4; ++j) acc[i][j] = (f32x4)(0.f);

    const int lr = lane & 15;
    const int lk = lane >> 4;

    for (int k0 = 0; k0 < DM; k0 += 32) {
#pragma unroll
        for (int i = 0; i < 2; ++i) {
            int c = tid * 2 + i;
            int r = c >> 2, kg = c & 3;
            *(uint4*)&As[r][kg * 8] =
                *(const uint4*)&Xb[(size_t)(brow + r) * DM + k0 + kg * 8];
            *(uint4*)&Bs[r][kg * 8] =
                *(const uint4*)&Wb[(size_t)(bcol + r) * DM + k0 + kg * 8];
        }
        __syncthreads();
        short8v af[4], bf[4];
#pragma unroll
        for (int mt = 0; mt < 4; ++mt)
            af[mt] = *(const short8v*)&As[wr * 64 + mt * 16 + lr][lk * 8];
#pragma unroll
        for (int nt = 0; nt < 4; ++nt)
            bf[nt] = *(const short8v*)&Bs[wc * 64 + nt * 16 + lr][lk * 8];
#pragma unroll
        for (int mt = 0; mt < 4; ++mt)
#pragma unroll
            for (int nt = 0; nt < 4; ++nt)
                acc[mt][nt] = __builtin_amdgcn_mfma_f32_16x16x32_bf16(
                    af[mt], bf[nt], acc[mt][nt], 0, 0, 0);
        __syncthreads();
    }

#pragma unroll
    for (int mt = 0; mt < 4; ++mt)
#pragma unroll
        for (int nt = 0; nt < 4; ++nt) {
            const int row0 = brow + wr * 64 + mt * 16 + lk * 4;
            const int col = bcol + wc * 64 + nt * 16 + lr;
#pragma unroll
            for (int j = 0; j < 4; ++j)
                C[(size_t)(row0 + j) * DM + col] = acc[mt][nt][j];
        }
}

// ---- Per (chunk, dgroup, batch): intra-chunk attention + chunk summaries ----
__global__ __launch_bounds__(256) void chunk_local(
    const float* __restrict__ Q, const float* __restrict__ Kmat,
    const float* __restrict__ V, const float* __restrict__ logit,
    float* __restrict__ OI, float* __restrict__ DI,
    float* __restrict__ KV, float* __restrict__ KZ)
{
    const int chunk = blockIdx.x;
    const int dg = blockIdx.y;
    const int b = blockIdx.z;
    const int tid = threadIdx.x;
    const int t0 = chunk * CHK;
    const float ld = get_ld(logit);

    __shared__ float Qs[CHK][MM + 1];
    __shared__ float Ks[CHK][MM + 1];
    __shared__ float As[CHK][CHK + 1];
    __shared__ float Vt[16][128];
    __shared__ float wk[CHK];

    const float* Qb = Q + ((size_t)b * LSEQ + t0) * MM;
    const float* Kb = Kmat + ((size_t)b * LSEQ + t0) * MM;
#pragma unroll
    for (int l = 0; l < 16; ++l) {
        int e = tid + l * 256;
        int r = e >> 6, m = e & 63;
        Qs[r][m] = Qb[e];
        Ks[r][m] = Kb[e];
    }
    if (tid < CHK) {
        wk[tid] = expf(cpos(ld, t0 + CHK - 1) - cpos(ld, t0 + tid));
    }
    __syncthreads();

    {
        const int t = tid >> 2, j = tid & 3;
        const float ct = cpos(ld, t0 + t);
#pragma unroll
        for (int ii = 0; ii < 16; ++ii) {
            int s = j + ii * 4;
            float a = 0.f;
            if (s <= t) {
#pragma unroll
                for (int m = 0; m < MM; ++m) a += Qs[t][m] * Ks[s][m];
                a *= expf(ct - cpos(ld, t0 + s));
            }
            As[t][s] = a;
        }
    }
    __syncthreads();

    if (dg == 0 && tid < CHK) {
        float sden = 0.f;
#pragma unroll
        for (int s = 0; s < CHK; ++s) sden += As[tid][s];
        DI[(size_t)b * LSEQ + t0 + tid] = sden;
        float skz = 0.f;
#pragma unroll
        for (int s = 0; s < CHK; ++s) skz += wk[s] * Ks[s][tid];
        KZ[((size_t)b * NCHUNK + chunk) * MM + tid] = skz;
    }

    const int dcol = tid & 127;
    const int half = tid >> 7;
    const int dglob = dg * 128 + dcol;
    float accO[32], accKV[32];
#pragma unroll
    for (int i = 0; i < 32; ++i) { accO[i] = 0.f; accKV[i] = 0.f; }

    const float* Vb = V + ((size_t)b * LSEQ + t0) * DM + dg * 128;
    for (int s0 = 0; s0 < CHK; s0 += 16) {
        __syncthreads();
#pragma unroll
        for (int l = 0; l < 8; ++l) {
            int e = tid + l * 256;
            int s = e >> 7, dd = e & 127;
            Vt[s][dd] = Vb[(size_t)(s0 + s) * DM + dd];
        }
        __syncthreads();
#pragma unroll
        for (int s = 0; s < 16; ++s) {
            const int sg = s0 + s;
            const float v = Vt[s][dcol];
            const float vw = wk[sg] * v;
#pragma unroll
            for (int t = 0; t < 32; ++t) accO[t] += As[half * 32 + t][sg] * v;
#pragma unroll
            for (int m = 0; m < 32; ++m) accKV[m] += Ks[sg][half * 32 + m] * vw;
        }
    }

    float* OIb = OI + ((size_t)b * LSEQ + t0) * DM;
#pragma unroll
    for (int t = 0; t < 32; ++t)
        OIb[(size_t)(half * 32 + t) * DM + dglob] = accO[t];
    float* KVb = KV + ((size_t)b * NCHUNK + chunk) * MM * DM;
#pragma unroll
    for (int m = 0; m < 32; ++m)
        KVb[(size_t)(half * 32 + m) * DM + dglob] = accKV[m];
}

// ---- Sequential scan over chunks ----
__global__ __launch_bounds__(256) void state_scan(
    const float* __restrict__ KV, const float* __restrict__ KZ,
    const float* __restrict__ logit,
    float* __restrict__ SS, float* __restrict__ ZS)
{
    const int g = blockIdx.x * 256 + threadIdx.x;
    const int b = g >> 15;
    const int rem = g & 32767;
    const int m = rem >> 9;
    const int d = rem & 511;
    const float ld = get_ld(logit);

    float s = 0.f;
    float zs = 0.f;
    const bool doz = (d == 0);
    float cprev = 0.f;
    for (int i = 0; i < NCHUNK; ++i) {
        const float ce = cpos(ld, i * CHK + CHK - 1);
        const float lam = expf(ce - cprev);
        cprev = ce;
        const size_t idx = (((size_t)b * NCHUNK + i) * MM + m) * DM + d;
        SS[idx] = s;
        s = lam * s + KV[idx];
        if (doz) {
            const int zi = (b * NCHUNK + i) * MM + m;
            ZS[zi] = zs;
            zs = lam * zs + KZ[zi];
        }
    }
}

// ---- Inter-chunk combine, parallel over d-slices ----
__global__ __launch_bounds__(256) void chunk_combine(
    const float* __restrict__ Q, const float* __restrict__ SS,
    const float* __restrict__ ZS, float* __restrict__ OIN,
    const float* __restrict__ DI, const float* __restrict__ logit,
    float* __restrict__ DEN)
{
    const int chunk = blockIdx.x;
    const int dg = blockIdx.y;
    const int b = blockIdx.z;
    const int tid = threadIdx.x;
    const int t0 = chunk * CHK;
    const float ld = get_ld(logit);

    __shared__ float Qs[CHK][68];    // padded, 16B-aligned rows
    __shared__ float Ssh[MM][132];   // 128-wide slice, padded
    __shared__ float gv[CHK];

    // stage Q chunk (64x64) as float4
    {
        const float* Qb = Q + ((size_t)b * LSEQ + t0) * MM;
#pragma unroll
        for (int l = 0; l < 4; ++l) {
            int e4 = tid + l * 256;
            int r = e4 >> 4, m4 = e4 & 15;
            float4 v = ((const float4*)Qb)[e4];
            *(float4*)&Qs[r][m4 * 4] = v;
        }
    }
    // stage S_prev slice (64 x 128) as float4
    {
        const float* Sp = SS + (((size_t)b * NCHUNK + chunk) * MM) * DM + dg * 128;
#pragma unroll
        for (int l = 0; l < 8; ++l) {
            int e4 = tid + l * 256;
            int m = e4 >> 5, dd4 = e4 & 31;
            float4 v = *(const float4*)&Sp[(size_t)m * DM + dd4 * 4];
            *(float4*)&Ssh[m][dd4 * 4] = v;
        }
    }
    const float cprev = (chunk > 0) ? cpos(ld, t0 - 1) : 0.f;
    if (tid < CHK) gv[tid] = expf(cpos(ld, t0 + tid) - cprev);
    __syncthreads();

    if (dg == 0 && tid < CHK) {
        const float* zp = ZS + ((size_t)b * NCHUNK + chunk) * MM;
        float a = 0.f;
#pragma unroll
        for (int m = 0; m < MM; ++m) a += Qs[tid][m] * zp[m];
        DEN[(size_t)b * LSEQ + t0 + tid] =
            gv[tid] * a + DI[(size_t)b * LSEQ + t0 + tid] + 1e-6f;
    }

    // each thread: 4 t-rows x 8 d-cols
    const int tg = tid >> 4;   // 0..15 -> t rows tg*4..tg*4+3
    const int dl = tid & 15;   // d cols dl + 16*j
    float acc[4][8];
#pragma unroll
    for (int i = 0; i < 4; ++i)
#pragma unroll
        for (int j = 0; j < 8; ++j) acc[i][j] = 0.f;

    for (int m = 0; m < MM; ++m) {
        float qv[4], sv[8];
#pragma unroll
        for (int i = 0; i < 4; ++i) qv[i] = Qs[tg * 4 + i][m];
#pragma unroll
        for (int j = 0; j < 8; ++j) sv[j] = Ssh[m][dl + 16 * j];
#pragma unroll
        for (int i = 0; i < 4; ++i)
#pragma unroll
            for (int j = 0; j < 8; ++j) acc[i][j] += qv[i] * sv[j];
    }

    float* OIb = OIN + ((size_t)b * LSEQ + t0) * DM + dg * 128;
#pragma unroll
    for (int i = 0; i < 4; ++i) {
        const int t = tg * 4 + i;
        const float g = gv[t];
#pragma unroll
        for (int j = 0; j < 8; ++j) {
            const size_t o = (size_t)t * DM + dl + 16 * j;
            OIb[o] = g * acc[i][j] + OIb[o];
        }
    }
}

// ---- RMS norm rows -> bf16 output for O-projection ----
__global__ __launch_bounds__(256) void rms_kernel(
    const float* __restrict__ NUM, const float* __restrict__ DEN,
    const float* __restrict__ w, unsigned short* __restrict__ NRM)
{
    const int row = blockIdx.x;
    const int tid = threadIdx.x;
    const float* nr = NUM + (size_t)row * DM;
    const float den = DEN[row];
    const float inv = 1.0f / den;
    const float x0 = nr[tid] * inv;
    const float x1 = nr[tid + 256] * inv;
    float ss = x0 * x0 + x1 * x1;
#pragma unroll
    for (int i = 1; i < 64; i <<= 1) ss += __shfl_xor(ss, i, 64);
    __shared__ float red[4];
    const int lane = tid & 63, wv = tid >> 6;
    if (lane == 0) red[wv] = ss;
    __syncthreads();
    const float tot = red[0] + red[1] + red[2] + red[3];
    const float rms = sqrtf(tot * (1.0f / (float)DM) + 1e-6f);
    const float rinv = 1.0f / rms;
    NRM[(size_t)row * DM + tid] = f2bf(x0 * rinv * w[tid]);
    NRM[(size_t)row * DM + tid + 256] = f2bf(x1 * rinv * w[tid + 256]);
}

extern "C" void kernel_launch(void* const* d_in, const int* in_sizes, int n_in,
                              void* d_out, int out_size, void* d_ws, size_t ws_size,
                              hipStream_t stream) {
    const float* x      = (const float*)d_in[0];
    const float* W_q    = (const float*)d_in[1];
    const float* W_k    = (const float*)d_in[2];
    const float* W_v    = (const float*)d_in[3];
    const float* W_o    = (const float*)d_in[4];
    const float* logit  = (const float*)d_in[5];
    const float* norm_w = (const float*)d_in[6];
    float* out = (float*)d_out;

    const size_t BLM = (size_t)NB * LSEQ * MM;      // 262144
    const size_t BLD = (size_t)NB * LSEQ * DM;      // 2097152
    const size_t BL  = (size_t)NB * LSEQ;           // 4096
    const size_t BNCMD = (size_t)NB * NCHUNK * MM * DM;
    const size_t BNCM  = (size_t)NB * NCHUNK * MM;
    const size_t WSZ = (size_t)DM * DM;             // 262144

    float* ws = (float*)d_ws;
    float* Qp  = ws;
    float* Kp  = Qp + BLM;
    float* Vp  = Kp + BLM;
    float* OIp = Vp + BLD;
    float* DIp = OIp + BLD;
    float* KVp = DIp + BL;
    float* KZp = KVp + BNCMD;
    float* SSp = KZp + BNCM;
    float* ZSp = SSp + BNCMD;
    float* DENp = ZSp + BNCM;
    unsigned short* Xb   = (unsigned short*)(DENp + BL);
    unsigned short* Wvb  = Xb + BLD;
    unsigned short* Wob  = Wvb + WSZ;
    unsigned short* NRMb = Wob + WSZ;

    const int rows = NB * LSEQ;   // 4096

    // bf16 conversions
    cvt_bf16<<<dim3((int)(BLD / 1024)), 256, 0, stream>>>(x, Xb, (int)(BLD / 4));
    cvt_bf16<<<dim3((int)(WSZ / 1024)), 256, 0, stream>>>(W_v, Wvb, (int)(WSZ / 4));
    cvt_bf16<<<dim3((int)(WSZ / 1024)), 256, 0, stream>>>(W_o, Wob, (int)(WSZ / 4));

    // Projections
    gemm_qk<<<dim3(rows / 64, 2), 256, 0, stream>>>(x, W_q, W_k, Qp, Kp);
    gemm_mfma_bt<<<dim3(rows / 128, DM / 128), 256, 0, stream>>>(Xb, Wvb, Vp);

    // Intra-chunk attention + chunk summaries
    chunk_local<<<dim3(NCHUNK, 4, NB), 256, 0, stream>>>(Qp, Kp, Vp, logit,
                                                         OIp, DIp, KVp, KZp);
    // Sequential state scan over chunks
    state_scan<<<dim3(256), 256, 0, stream>>>(KVp, KZp, logit, SSp, ZSp);
    // Inter-chunk combine
    chunk_combine<<<dim3(NCHUNK, 4, NB), 256, 0, stream>>>(Qp, SSp, ZSp, OIp, DIp,
                                                           logit, DENp);
    // RMS norm -> bf16
    rms_kernel<<<dim3(rows), 256, 0, stream>>>(OIp, DENp, norm_w, NRMb);
    // Output projection (bf16 MFMA)
    gemm_mfma_bt<<<dim3(rows / 128, DM / 128), 256, 0, stream>>>(NRMb, Wob, out);
}

// Round 3
// 86.682 us; speedup vs baseline: 4.6141x; 1.6522x over previous
//
#include <hip/hip_runtime.h>
#include <math.h>

#define NB 2
#define LSEQ 2048
#define DM 512
#define MM 64
#define CHK 64
#define NCHUNK 32

typedef __attribute__((ext_vector_type(8))) short short8v;
typedef __attribute__((ext_vector_type(4))) float f32x4;

__device__ __forceinline__ float get_ld(const float* __restrict__ logit) {
    float lg = *logit;
    float dec = 1.0f / (1.0f + expf(-lg));
    dec = fmaxf(dec, 1e-6f);
    return logf(dec);
}
__device__ __forceinline__ float cpos(float ld, int t) {
    return fminf(fmaxf(ld * (float)t, -20.0f), 20.0f);
}
__device__ __forceinline__ float phi_fn(float v) {
    return v > 0.0f ? v + 1.0f : expf(v);
}
__device__ __forceinline__ unsigned short f2bf(float f) {
    unsigned int u = __float_as_uint(f);
    u += 0x7FFFu + ((u >> 16) & 1u);   // RNE
    return (unsigned short)(u >> 16);
}
__device__ __forceinline__ float bf2f(unsigned short h) {
    unsigned int u = ((unsigned int)h) << 16;
    return __uint_as_float(u);
}

// ---- fused f32 -> bf16 convert for all bf16 operands ----
__global__ __launch_bounds__(256) void cvt_all(
    const float* __restrict__ x, const float* __restrict__ wv,
    const float* __restrict__ wo, const float* __restrict__ wq,
    const float* __restrict__ wkk,
    unsigned short* __restrict__ xb, unsigned short* __restrict__ wvb,
    unsigned short* __restrict__ wob, unsigned short* __restrict__ wqb,
    unsigned short* __restrict__ wkb)
{
    const int bid = blockIdx.x;
    const float* src;
    unsigned short* dst;
    int i4;
    if (bid < 2048)      { src = x;   dst = xb;  i4 = bid * 256 + threadIdx.x; }
    else if (bid < 2304) { src = wv;  dst = wvb; i4 = (bid - 2048) * 256 + threadIdx.x; }
    else if (bid < 2560) { src = wo;  dst = wob; i4 = (bid - 2304) * 256 + threadIdx.x; }
    else if (bid < 2592) { src = wq;  dst = wqb; i4 = (bid - 2560) * 256 + threadIdx.x; }
    else                 { src = wkk; dst = wkb; i4 = (bid - 2592) * 256 + threadIdx.x; }
    float4 v = ((const float4*)src)[i4];
    ushort4 o;
    o.x = f2bf(v.x); o.y = f2bf(v.y); o.z = f2bf(v.z); o.w = f2bf(v.w);
    ((ushort4*)dst)[i4] = o;
}

// ---- Q/K projection via MFMA: 128-row tile x 128 cols (Wq | Wk stacked) ----
__global__ __launch_bounds__(256) void gemm_qk_mfma(
    const unsigned short* __restrict__ Xb, const unsigned short* __restrict__ Wqb,
    const unsigned short* __restrict__ Wkb, float* __restrict__ Qf,
    unsigned short* __restrict__ Qh, unsigned short* __restrict__ Kh)
{
    __shared__ unsigned short Asm[128][40];
    __shared__ unsigned short Bsm[128][40];
    const int brow = blockIdx.x * 128;
    const int tid = threadIdx.x;
    const int lane = tid & 63, wid = tid >> 6;
    const int wr = wid >> 1, wc = wid & 1;
    const int lr = lane & 15, lk = lane >> 4;

    f32x4 acc[4][4];
#pragma unroll
    for (int i = 0; i < 4; ++i)
#pragma unroll
        for (int j = 0; j < 4; ++j) acc[i][j] = (f32x4)(0.f);

    for (int k0 = 0; k0 < DM; k0 += 32) {
#pragma unroll
        for (int i = 0; i < 2; ++i) {
            int c = tid * 2 + i;
            int r = c >> 2, kg = c & 3;
            *(uint4*)&Asm[r][kg * 8] =
                *(const uint4*)&Xb[(size_t)(brow + r) * DM + k0 + kg * 8];
            const unsigned short* wsrc = (r < 64)
                ? &Wqb[(size_t)r * DM + k0 + kg * 8]
                : &Wkb[(size_t)(r - 64) * DM + k0 + kg * 8];
            *(uint4*)&Bsm[r][kg * 8] = *(const uint4*)wsrc;
        }
        __syncthreads();
        short8v af[4], bf[4];
#pragma unroll
        for (int mt = 0; mt < 4; ++mt)
            af[mt] = *(const short8v*)&Asm[wr * 64 + mt * 16 + lr][lk * 8];
#pragma unroll
        for (int nt = 0; nt < 4; ++nt)
            bf[nt] = *(const short8v*)&Bsm[wc * 64 + nt * 16 + lr][lk * 8];
#pragma unroll
        for (int mt = 0; mt < 4; ++mt)
#pragma unroll
            for (int nt = 0; nt < 4; ++nt)
                acc[mt][nt] = __builtin_amdgcn_mfma_f32_16x16x32_bf16(
                    af[mt], bf[nt], acc[mt][nt], 0, 0, 0);
        __syncthreads();
    }

#pragma unroll
    for (int mt = 0; mt < 4; ++mt)
#pragma unroll
        for (int nt = 0; nt < 4; ++nt) {
            const int col = wc * 64 + nt * 16 + lr;
#pragma unroll
            for (int j = 0; j < 4; ++j) {
                const int row = brow + wr * 64 + mt * 16 + lk * 4 + j;
                float v = phi_fn(acc[mt][nt][j]);
                if (col < 64) {
                    v *= 0.125f;
                    Qf[(size_t)row * MM + col] = v;
                    Qh[(size_t)row * MM + col] = f2bf(v);
                } else {
                    Kh[(size_t)row * MM + (col - 64)] = f2bf(v);
                }
            }
        }
}

// ---- bf16 MFMA GEMM: C(rows x 512) = Xb @ Wb^T; OB=1 -> bf16 out ----
template <int OB>
__global__ __launch_bounds__(256) void gemm_mfma_bt(
    const unsigned short* __restrict__ Xb, const unsigned short* __restrict__ Wb,
    void* __restrict__ Cv)
{
    __shared__ unsigned short As[128][40];
    __shared__ unsigned short Bs[128][40];
    const int brow = blockIdx.x * 128;
    const int bcol = blockIdx.y * 128;
    const int tid = threadIdx.x;
    const int lane = tid & 63, wid = tid >> 6;
    const int wr = wid >> 1, wc = wid & 1;
    const int lr = lane & 15, lk = lane >> 4;

    f32x4 acc[4][4];
#pragma unroll
    for (int i = 0; i < 4; ++i)
#pragma unroll
        for (int j = 0; j < 4; ++j) acc[i][j] = (f32x4)(0.f);

    for (int k0 = 0; k0 < DM; k0 += 32) {
#pragma unroll
        for (int i = 0; i < 2; ++i) {
            int c = tid * 2 + i;
            int r = c >> 2, kg = c & 3;
            *(uint4*)&As[r][kg * 8] =
                *(const uint4*)&Xb[(size_t)(brow + r) * DM + k0 + kg * 8];
            *(uint4*)&Bs[r][kg * 8] =
                *(const uint4*)&Wb[(size_t)(bcol + r) * DM + k0 + kg * 8];
        }
        __syncthreads();
        short8v af[4], bf[4];
#pragma unroll
        for (int mt = 0; mt < 4; ++mt)
            af[mt] = *(const short8v*)&As[wr * 64 + mt * 16 + lr][lk * 8];
#pragma unroll
        for (int nt = 0; nt < 4; ++nt)
            bf[nt] = *(const short8v*)&Bs[wc * 64 + nt * 16 + lr][lk * 8];
#pragma unroll
        for (int mt = 0; mt < 4; ++mt)
#pragma unroll
            for (int nt = 0; nt < 4; ++nt)
                acc[mt][nt] = __builtin_amdgcn_mfma_f32_16x16x32_bf16(
                    af[mt], bf[nt], acc[mt][nt], 0, 0, 0);
        __syncthreads();
    }

#pragma unroll
    for (int mt = 0; mt < 4; ++mt)
#pragma unroll
        for (int nt = 0; nt < 4; ++nt) {
            const int row0 = brow + wr * 64 + mt * 16 + lk * 4;
            const int col = bcol + wc * 64 + nt * 16 + lr;
#pragma unroll
            for (int j = 0; j < 4; ++j) {
                if (OB)
                    ((unsigned short*)Cv)[(size_t)(row0 + j) * DM + col] =
                        f2bf(acc[mt][nt][j]);
                else
                    ((float*)Cv)[(size_t)(row0 + j) * DM + col] = acc[mt][nt][j];
            }
        }
}

// ---- intra-chunk attention + summaries, all MFMA ----
__global__ __launch_bounds__(256) void chunk_local_mfma(
    const unsigned short* __restrict__ Qb, const unsigned short* __restrict__ Kb,
    const unsigned short* __restrict__ Vb, const float* __restrict__ logit,
    float* __restrict__ OI, float* __restrict__ DI,
    float* __restrict__ KV, float* __restrict__ KZ)
{
    const int chunk = blockIdx.x, dg = blockIdx.y, b = blockIdx.z;
    const int tid = threadIdx.x;
    const int lane = tid & 63, wid = tid >> 6;
    const int wr = wid >> 1, wc = wid & 1;
    const int lr = lane & 15, lk = lane >> 4;
    const int t0 = chunk * CHK;
    const float ld = get_ld(logit);

    __shared__ unsigned short Qs[64][72];   // contiguous b128 frag reads
    __shared__ unsigned short Ks[64][72];
    __shared__ unsigned short As[64][72];
    __shared__ unsigned short Kws[64][66];  // strided frag reads (pad 66: conflict-free)
    __shared__ unsigned short Vs[64][134];  // strided frag reads (pad 134: conflict-free)
    __shared__ float wks[64];
    __shared__ float cps[64];
    __shared__ float DIsh[64];

    if (tid < 64) {
        const float c = cpos(ld, t0 + tid);
        cps[tid] = c;
        wks[tid] = expf(cpos(ld, t0 + CHK - 1) - c);
        DIsh[tid] = 0.f;
    }
    __syncthreads();

    // stage Q, K (row-major) + wk-scaled K
    const unsigned short* Qg = Qb + ((size_t)b * LSEQ + t0) * MM;
    const unsigned short* Kg = Kb + ((size_t)b * LSEQ + t0) * MM;
#pragma unroll
    for (int l = 0; l < 2; ++l) {
        const int e = tid + l * 256;
        const int r = e >> 3, gq = e & 7;
        *(uint4*)&Qs[r][gq * 8] = *(const uint4*)(Qg + (size_t)e * 8);
        uint4 kraw = *(const uint4*)(Kg + (size_t)e * 8);
        *(uint4*)&Ks[r][gq * 8] = kraw;
        const float w = wks[r];
        const unsigned short* kp = (const unsigned short*)&kraw;
#pragma unroll
        for (int p = 0; p < 4; ++p) {
            ushort2 o;
            o.x = f2bf(w * bf2f(kp[2 * p]));
            o.y = f2bf(w * bf2f(kp[2 * p + 1]));
            *(ushort2*)&Kws[r][gq * 8 + 2 * p] = o;
        }
    }
    // stage V slice (row-major [s][128])
    const unsigned short* Vg = Vb + ((size_t)b * LSEQ + t0) * DM + dg * 128;
#pragma unroll
    for (int l = 0; l < 4; ++l) {
        const int e = tid + l * 256;
        const int s = e >> 4, gg = e & 15;
        uint4 vr = *(const uint4*)(Vg + (size_t)s * DM + gg * 8);
        const unsigned short* vp = (const unsigned short*)&vr;
#pragma unroll
        for (int p = 0; p < 4; ++p) {
            ushort2 o;
            o.x = vp[2 * p]; o.y = vp[2 * p + 1];
            *(ushort2*)&Vs[s][gg * 8 + 2 * p] = o;
        }
    }
    __syncthreads();

    // S = Q K^T (wave quadrant 32x32)
    f32x4 sacc[2][2];
#pragma unroll
    for (int i = 0; i < 2; ++i)
#pragma unroll
        for (int j = 0; j < 2; ++j) sacc[i][j] = (f32x4)(0.f);
#pragma unroll
    for (int ks = 0; ks < 2; ++ks) {
        short8v qa[2], kb2[2];
#pragma unroll
        for (int mt = 0; mt < 2; ++mt)
            qa[mt] = *(const short8v*)&Qs[wr * 32 + mt * 16 + lr][ks * 32 + lk * 8];
#pragma unroll
        for (int nt = 0; nt < 2; ++nt)
            kb2[nt] = *(const short8v*)&Ks[wc * 32 + nt * 16 + lr][ks * 32 + lk * 8];
#pragma unroll
        for (int mt = 0; mt < 2; ++mt)
#pragma unroll
            for (int nt = 0; nt < 2; ++nt)
                sacc[mt][nt] = __builtin_amdgcn_mfma_f32_16x16x32_bf16(
                    qa[mt], kb2[nt], sacc[mt][nt], 0, 0, 0);
    }

    // decay mask + fp32 row sums + bf16 A write
#pragma unroll
    for (int mt = 0; mt < 2; ++mt) {
#pragma unroll
        for (int j = 0; j < 4; ++j) {
            const int t = wr * 32 + mt * 16 + lk * 4 + j;
            const float ct = cps[t];
            float rowpart = 0.f;
#pragma unroll
            for (int nt = 0; nt < 2; ++nt) {
                const int s = wc * 32 + nt * 16 + lr;
                float v = sacc[mt][nt][j];
                v = (s <= t) ? v * expf(ct - cps[s]) : 0.f;
                rowpart += v;
                As[t][s] = f2bf(v);
            }
            rowpart += __shfl_xor(rowpart, 1);
            rowpart += __shfl_xor(rowpart, 2);
            rowpart += __shfl_xor(rowpart, 4);
            rowpart += __shfl_xor(rowpart, 8);
            if (lr == 0) atomicAdd(&DIsh[t], rowpart);
        }
    }
    __syncthreads();

    if (dg == 0) {
        if (tid < 64) DI[(size_t)b * LSEQ + t0 + tid] = DIsh[tid];
        if (tid >= 64 && tid < 128) {
            const int m = tid - 64;
            float z = 0.f;
#pragma unroll
            for (int s = 0; s < 64; ++s) z += wks[s] * bf2f(Ks[s][m]);
            KZ[((size_t)b * NCHUNK + chunk) * MM + m] = z;
        }
    }

    // O = A.V and KVc = Kw^T.V (shared V B-frags)
    f32x4 aO[2][4], aK[2][4];
#pragma unroll
    for (int i = 0; i < 2; ++i)
#pragma unroll
        for (int j = 0; j < 4; ++j) { aO[i][j] = (f32x4)(0.f); aK[i][j] = (f32x4)(0.f); }

#pragma unroll
    for (int ks = 0; ks < 2; ++ks) {
        short8v vf[4];
#pragma unroll
        for (int nt = 0; nt < 4; ++nt) {
            unsigned short* vp = (unsigned short*)&vf[nt];
            const int n = wc * 64 + nt * 16 + lr;
#pragma unroll
            for (int e = 0; e < 8; ++e)
                vp[e] = Vs[ks * 32 + lk * 8 + e][n];
        }
        short8v af2[2], kf2[2];
#pragma unroll
        for (int mt = 0; mt < 2; ++mt) {
            const int row = wr * 32 + mt * 16 + lr;
            af2[mt] = *(const short8v*)&As[row][ks * 32 + lk * 8];
            unsigned short* kp = (unsigned short*)&kf2[mt];
#pragma unroll
            for (int e = 0; e < 8; ++e)
                kp[e] = Kws[ks * 32 + lk * 8 + e][row];
        }
#pragma unroll
        for (int mt = 0; mt < 2; ++mt)
#pragma unroll
            for (int nt = 0; nt < 4; ++nt) {
                aO[mt][nt] = __builtin_amdgcn_mfma_f32_16x16x32_bf16(
                    af2[mt], vf[nt], aO[mt][nt], 0, 0, 0);
                aK[mt][nt] = __builtin_amdgcn_mfma_f32_16x16x32_bf16(
                    kf2[mt], vf[nt], aK[mt][nt], 0, 0, 0);
            }
    }

    float* OIb = OI + ((size_t)b * LSEQ + t0) * DM + dg * 128;
    float* KVb = KV + ((size_t)b * NCHUNK + chunk) * MM * DM + dg * 128;
#pragma unroll
    for (int mt = 0; mt < 2; ++mt)
#pragma unroll
        for (int nt = 0; nt < 4; ++nt) {
            const int col = wc * 64 + nt * 16 + lr;
#pragma unroll
            for (int j = 0; j < 4; ++j) {
                const int row = wr * 32 + mt * 16 + lk * 4 + j;
                OIb[(size_t)row * DM + col] = aO[mt][nt][j];
                KVb[(size_t)row * DM + col] = aK[mt][nt][j];
            }
        }
}

// ---- sequential scan over chunks (register-resident) ----
__global__ __launch_bounds__(256) void state_scan(
    const float* __restrict__ KV, const float* __restrict__ KZ,
    const float* __restrict__ logit,
    float* __restrict__ SS, float* __restrict__ ZS)
{
    const int g = blockIdx.x * 256 + threadIdx.x;
    const int b = g >> 15;
    const int rem = g & 32767;
    const int m = rem >> 9;
    const int d = rem & 511;
    const float ld = get_ld(logit);
    const size_t base = (((size_t)b * NCHUNK) * MM + m) * DM + d;
    const size_t cstride = (size_t)MM * DM;

    float v[NCHUNK];
#pragma unroll
    for (int i = 0; i < NCHUNK; ++i) v[i] = KV[base + (size_t)i * cstride];

    float s = 0.f, cprev = 0.f;
#pragma unroll
    for (int i = 0; i < NCHUNK; ++i) {
        const float ce = cpos(ld, i * CHK + CHK - 1);
        const float lam = expf(ce - cprev);
        cprev = ce;
        SS[base + (size_t)i * cstride] = s;
        s = lam * s + v[i];
    }
    if (d == 0) {
        float zs = 0.f;
        cprev = 0.f;
#pragma unroll
        for (int i = 0; i < NCHUNK; ++i) {
            const float ce = cpos(ld, i * CHK + CHK - 1);
            const float lam = expf(ce - cprev);
            cprev = ce;
            const int zi = (b * NCHUNK + i) * MM + m;
            ZS[zi] = zs;
            zs = lam * zs + KZ[zi];
        }
    }
}

// ---- inter-chunk combine (VALU register tile) ----
__global__ __launch_bounds__(256) void chunk_combine(
    const float* __restrict__ Q, const float* __restrict__ SS,
    const float* __restrict__ ZS, float* __restrict__ OIN,
    const float* __restrict__ DI, const float* __restrict__ logit,
    float* __restrict__ DEN)
{
    const int chunk = blockIdx.x;
    const int dg = blockIdx.y;
    const int b = blockIdx.z;
    const int tid = threadIdx.x;
    const int t0 = chunk * CHK;
    const float ld = get_ld(logit);

    __shared__ float Qs[CHK][68];
    __shared__ float Ssh[MM][132];
    __shared__ float gv[CHK];

    {
        const float* Qb = Q + ((size_t)b * LSEQ + t0) * MM;
#pragma unroll
        for (int l = 0; l < 4; ++l) {
            int e4 = tid + l * 256;
            int r = e4 >> 4, m4 = e4 & 15;
            float4 v = ((const float4*)Qb)[e4];
            *(float4*)&Qs[r][m4 * 4] = v;
        }
    }
    {
        const float* Sp = SS + (((size_t)b * NCHUNK + chunk) * MM) * DM + dg * 128;
#pragma unroll
        for (int l = 0; l < 8; ++l) {
            int e4 = tid + l * 256;
            int m = e4 >> 5, dd4 = e4 & 31;
            float4 v = *(const float4*)&Sp[(size_t)m * DM + dd4 * 4];
            *(float4*)&Ssh[m][dd4 * 4] = v;
        }
    }
    const float cprev = (chunk > 0) ? cpos(ld, t0 - 1) : 0.f;
    if (tid < CHK) gv[tid] = expf(cpos(ld, t0 + tid) - cprev);
    __syncthreads();

    if (dg == 0 && tid < CHK) {
        const float* zp = ZS + ((size_t)b * NCHUNK + chunk) * MM;
        float a = 0.f;
#pragma unroll
        for (int m = 0; m < MM; ++m) a += Qs[tid][m] * zp[m];
        DEN[(size_t)b * LSEQ + t0 + tid] =
            gv[tid] * a + DI[(size_t)b * LSEQ + t0 + tid] + 1e-6f;
    }

    const int tg = tid >> 4;
    const int dl = tid & 15;
    float acc[4][8];
#pragma unroll
    for (int i = 0; i < 4; ++i)
#pragma unroll
        for (int j = 0; j < 8; ++j) acc[i][j] = 0.f;

    for (int m = 0; m < MM; ++m) {
        float qv[4], sv[8];
#pragma unroll
        for (int i = 0; i < 4; ++i) qv[i] = Qs[tg * 4 + i][m];
#pragma unroll
        for (int j = 0; j < 8; ++j) sv[j] = Ssh[m][dl + 16 * j];
#pragma unroll
        for (int i = 0; i < 4; ++i)
#pragma unroll
            for (int j = 0; j < 8; ++j) acc[i][j] += qv[i] * sv[j];
    }

    float* OIb = OIN + ((size_t)b * LSEQ + t0) * DM + dg * 128;
#pragma unroll
    for (int i = 0; i < 4; ++i) {
        const int t = tg * 4 + i;
        const float g = gv[t];
#pragma unroll
        for (int j = 0; j < 8; ++j) {
            const size_t o = (size_t)t * DM + dl + 16 * j;
            OIb[o] = g * acc[i][j] + OIb[o];
        }
    }
}

// ---- RMS norm rows -> bf16 for O-projection ----
__global__ __launch_bounds__(256) void rms_kernel(
    const float* __restrict__ NUM, const float* __restrict__ DEN,
    const float* __restrict__ w, unsigned short* __restrict__ NRM)
{
    const int row = blockIdx.x;
    const int tid = threadIdx.x;
    const float* nr = NUM + (size_t)row * DM;
    const float den = DEN[row];
    const float inv = 1.0f / den;
    const float x0 = nr[tid] * inv;
    const float x1 = nr[tid + 256] * inv;
    float ss = x0 * x0 + x1 * x1;
#pragma unroll
    for (int i = 1; i < 64; i <<= 1) ss += __shfl_xor(ss, i, 64);
    __shared__ float red[4];
    const int lane = tid & 63, wv = tid >> 6;
    if (lane == 0) red[wv] = ss;
    __syncthreads();
    const float tot = red[0] + red[1] + red[2] + red[3];
    const float rms = sqrtf(tot * (1.0f / (float)DM) + 1e-6f);
    const float rinv = 1.0f / rms;
    NRM[(size_t)row * DM + tid] = f2bf(x0 * rinv * w[tid]);
    NRM[(size_t)row * DM + tid + 256] = f2bf(x1 * rinv * w[tid + 256]);
}

extern "C" void kernel_launch(void* const* d_in, const int* in_sizes, int n_in,
                              void* d_out, int out_size, void* d_ws, size_t ws_size,
                              hipStream_t stream) {
    const float* x      = (const float*)d_in[0];
    const float* W_q    = (const float*)d_in[1];
    const float* W_k    = (const float*)d_in[2];
    const float* W_v    = (const float*)d_in[3];
    const float* W_o    = (const float*)d_in[4];
    const float* logit  = (const float*)d_in[5];
    const float* norm_w = (const float*)d_in[6];
    float* out = (float*)d_out;

    const size_t BLM = (size_t)NB * LSEQ * MM;        // 262144
    const size_t BLD = (size_t)NB * LSEQ * DM;        // 2097152
    const size_t BL  = (size_t)NB * LSEQ;             // 4096
    const size_t BNCMD = (size_t)NB * NCHUNK * MM * DM; // 2097152
    const size_t BNCM  = (size_t)NB * NCHUNK * MM;    // 4096
    const size_t WSZ = (size_t)DM * DM;               // 262144

    float* ws = (float*)d_ws;
    float* Qp   = ws;
    float* OIp  = Qp + BLM;
    float* DIp  = OIp + BLD;
    float* KVp  = DIp + BL;
    float* KZp  = KVp + BNCMD;
    float* SSp  = KZp + BNCM;
    float* ZSp  = SSp + BNCMD;
    float* DENp = ZSp + BNCM;
    unsigned short* Xb   = (unsigned short*)(DENp + BL);
    unsigned short* Wvb  = Xb + BLD;
    unsigned short* Wob  = Wvb + WSZ;
    unsigned short* Wqb  = Wob + WSZ;
    unsigned short* Wkb  = Wqb + (size_t)MM * DM;
    unsigned short* Qb16 = Wkb + (size_t)MM * DM;
    unsigned short* Kb16 = Qb16 + BLM;
    unsigned short* Vb16 = Kb16 + BLM;
    unsigned short* NRMb = Vb16 + BLD;

    // bf16 conversions (one fused launch)
    cvt_all<<<dim3(2624), 256, 0, stream>>>(x, W_v, W_o, W_q, W_k,
                                            Xb, Wvb, Wob, Wqb, Wkb);
    // Q/K projection (MFMA) -> Q fp32 + Q/K bf16
    gemm_qk_mfma<<<dim3(32), 256, 0, stream>>>(Xb, Wqb, Wkb, Qp, Qb16, Kb16);
    // V projection (MFMA, bf16 out)
    gemm_mfma_bt<1><<<dim3(32, 4), 256, 0, stream>>>(Xb, Wvb, (void*)Vb16);
    // intra-chunk attention + summaries (MFMA)
    chunk_local_mfma<<<dim3(NCHUNK, 4, NB), 256, 0, stream>>>(
        Qb16, Kb16, Vb16, logit, OIp, DIp, KVp, KZp);
    // sequential state scan over chunks
    state_scan<<<dim3(256), 256, 0, stream>>>(KVp, KZp, logit, SSp, ZSp);
    // inter-chunk combine
    chunk_combine<<<dim3(NCHUNK, 4, NB), 256, 0, stream>>>(Qp, SSp, ZSp, OIp, DIp,
                                                           logit, DENp);
    // RMS norm -> bf16
    rms_kernel<<<dim3(NB * LSEQ), 256, 0, stream>>>(OIp, DENp, norm_w, NRMb);
    // output projection (MFMA, fp32 out)
    gemm_mfma_bt<0><<<dim3(32, 4), 256, 0, stream>>>(NRMb, Wob, (void*)out);
}

// Round 4
// 76.436 us; speedup vs baseline: 5.2326x; 1.1340x over previous
//
#include <hip/hip_runtime.h>
#include <math.h>

#define NB 2
#define LSEQ 2048
#define DM 512
#define MM 64
#define CHK 64
#define NCHUNK 32

typedef __attribute__((ext_vector_type(8))) short short8v;
typedef __attribute__((ext_vector_type(4))) float f32x4;

__device__ __forceinline__ float get_ld(const float* __restrict__ logit) {
    float lg = *logit;
    float dec = 1.0f / (1.0f + expf(-lg));
    dec = fmaxf(dec, 1e-6f);
    return logf(dec);
}
__device__ __forceinline__ float cpos(float ld, int t) {
    return fminf(fmaxf(ld * (float)t, -20.0f), 20.0f);
}
__device__ __forceinline__ float phi_fn(float v) {
    return v > 0.0f ? v + 1.0f : expf(v);
}
__device__ __forceinline__ unsigned short f2bf(float f) {
    unsigned int u = __float_as_uint(f);
    u += 0x7FFFu + ((u >> 16) & 1u);   // RNE
    return (unsigned short)(u >> 16);
}
__device__ __forceinline__ float bf2f(unsigned short h) {
    unsigned int u = ((unsigned int)h) << 16;
    return __uint_as_float(u);
}

// ---- fused f32 -> bf16 convert: x + all four weights ----
__global__ __launch_bounds__(256) void cvt_all(
    const float* __restrict__ x, const float* __restrict__ wv,
    const float* __restrict__ wo, const float* __restrict__ wq,
    const float* __restrict__ wkk,
    unsigned short* __restrict__ xb, unsigned short* __restrict__ wvb,
    unsigned short* __restrict__ wob, unsigned short* __restrict__ wqb,
    unsigned short* __restrict__ wkb)
{
    const int bid = blockIdx.x;
    const float* src;
    unsigned short* dst;
    int i4;
    if (bid < 2048)      { src = x;   dst = xb;  i4 = bid * 256 + threadIdx.x; }
    else if (bid < 2304) { src = wv;  dst = wvb; i4 = (bid - 2048) * 256 + threadIdx.x; }
    else if (bid < 2560) { src = wo;  dst = wob; i4 = (bid - 2304) * 256 + threadIdx.x; }
    else if (bid < 2592) { src = wq;  dst = wqb; i4 = (bid - 2560) * 256 + threadIdx.x; }
    else                 { src = wkk; dst = wkb; i4 = (bid - 2592) * 256 + threadIdx.x; }
    float4 v = ((const float4*)src)[i4];
    ushort4 o;
    o.x = f2bf(v.x); o.y = f2bf(v.y); o.z = f2bf(v.z); o.w = f2bf(v.w);
    ((ushort4*)dst)[i4] = o;
}

// ---- fused Q|K|V projection (MFMA). blockIdx.y==0: phi(QK); 1..4: V slice ----
__global__ __launch_bounds__(256) void gemm_proj(
    const unsigned short* __restrict__ Xb, const unsigned short* __restrict__ Wqb,
    const unsigned short* __restrict__ Wkb, const unsigned short* __restrict__ Wvb,
    unsigned short* __restrict__ Qh, unsigned short* __restrict__ Kh,
    unsigned short* __restrict__ Vh)
{
    __shared__ unsigned short Asm[128][40];
    __shared__ unsigned short Bsm[128][40];
    const int brow = blockIdx.x * 128;
    const int cb = blockIdx.y;          // 0=QK, 1..4 = V col slices
    const int tid = threadIdx.x;
    const int lane = tid & 63, wid = tid >> 6;
    const int wr = wid >> 1, wc = wid & 1;
    const int lr = lane & 15, lk = lane >> 4;

    f32x4 acc[4][4];
#pragma unroll
    for (int i = 0; i < 4; ++i)
#pragma unroll
        for (int j = 0; j < 4; ++j) acc[i][j] = (f32x4)(0.f);

    for (int k0 = 0; k0 < DM; k0 += 32) {
#pragma unroll
        for (int i = 0; i < 2; ++i) {
            int c = tid * 2 + i;
            int r = c >> 2, kg = c & 3;
            *(uint4*)&Asm[r][kg * 8] =
                *(const uint4*)&Xb[(size_t)(brow + r) * DM + k0 + kg * 8];
            const unsigned short* wsrc;
            if (cb == 0)
                wsrc = (r < 64) ? &Wqb[(size_t)r * DM + k0 + kg * 8]
                                : &Wkb[(size_t)(r - 64) * DM + k0 + kg * 8];
            else
                wsrc = &Wvb[(size_t)((cb - 1) * 128 + r) * DM + k0 + kg * 8];
            *(uint4*)&Bsm[r][kg * 8] = *(const uint4*)wsrc;
        }
        __syncthreads();
        short8v af[4], bf[4];
#pragma unroll
        for (int mt = 0; mt < 4; ++mt)
            af[mt] = *(const short8v*)&Asm[wr * 64 + mt * 16 + lr][lk * 8];
#pragma unroll
        for (int nt = 0; nt < 4; ++nt)
            bf[nt] = *(const short8v*)&Bsm[wc * 64 + nt * 16 + lr][lk * 8];
#pragma unroll
        for (int mt = 0; mt < 4; ++mt)
#pragma unroll
            for (int nt = 0; nt < 4; ++nt)
                acc[mt][nt] = __builtin_amdgcn_mfma_f32_16x16x32_bf16(
                    af[mt], bf[nt], acc[mt][nt], 0, 0, 0);
        __syncthreads();
    }

#pragma unroll
    for (int mt = 0; mt < 4; ++mt)
#pragma unroll
        for (int nt = 0; nt < 4; ++nt) {
            const int col = wc * 64 + nt * 16 + lr;
#pragma unroll
            for (int j = 0; j < 4; ++j) {
                const int row = brow + wr * 64 + mt * 16 + lk * 4 + j;
                float v = acc[mt][nt][j];
                if (cb == 0) {
                    v = phi_fn(v);
                    if (col < 64)
                        Qh[(size_t)row * MM + col] = f2bf(v * 0.125f);
                    else
                        Kh[(size_t)row * MM + (col - 64)] = f2bf(v);
                } else {
                    Vh[(size_t)row * DM + (cb - 1) * 128 + col] = f2bf(v);
                }
            }
        }
}

// ---- output GEMM: out(rows x 512) = NRMb @ Wob^T, fp32 out ----
__global__ __launch_bounds__(256) void gemm_out(
    const unsigned short* __restrict__ Xb, const unsigned short* __restrict__ Wb,
    float* __restrict__ C)
{
    __shared__ unsigned short As[128][40];
    __shared__ unsigned short Bs[128][40];
    const int brow = blockIdx.x * 128;
    const int bcol = blockIdx.y * 128;
    const int tid = threadIdx.x;
    const int lane = tid & 63, wid = tid >> 6;
    const int wr = wid >> 1, wc = wid & 1;
    const int lr = lane & 15, lk = lane >> 4;

    f32x4 acc[4][4];
#pragma unroll
    for (int i = 0; i < 4; ++i)
#pragma unroll
        for (int j = 0; j < 4; ++j) acc[i][j] = (f32x4)(0.f);

    for (int k0 = 0; k0 < DM; k0 += 32) {
#pragma unroll
        for (int i = 0; i < 2; ++i) {
            int c = tid * 2 + i;
            int r = c >> 2, kg = c & 3;
            *(uint4*)&As[r][kg * 8] =
                *(const uint4*)&Xb[(size_t)(brow + r) * DM + k0 + kg * 8];
            *(uint4*)&Bs[r][kg * 8] =
                *(const uint4*)&Wb[(size_t)(bcol + r) * DM + k0 + kg * 8];
        }
        __syncthreads();
        short8v af[4], bf[4];
#pragma unroll
        for (int mt = 0; mt < 4; ++mt)
            af[mt] = *(const short8v*)&As[wr * 64 + mt * 16 + lr][lk * 8];
#pragma unroll
        for (int nt = 0; nt < 4; ++nt)
            bf[nt] = *(const short8v*)&Bs[wc * 64 + nt * 16 + lr][lk * 8];
#pragma unroll
        for (int mt = 0; mt < 4; ++mt)
#pragma unroll
            for (int nt = 0; nt < 4; ++nt)
                acc[mt][nt] = __builtin_amdgcn_mfma_f32_16x16x32_bf16(
                    af[mt], bf[nt], acc[mt][nt], 0, 0, 0);
        __syncthreads();
    }

#pragma unroll
    for (int mt = 0; mt < 4; ++mt)
#pragma unroll
        for (int nt = 0; nt < 4; ++nt) {
            const int row0 = brow + wr * 64 + mt * 16 + lk * 4;
            const int col = bcol + wc * 64 + nt * 16 + lr;
#pragma unroll
            for (int j = 0; j < 4; ++j)
                C[(size_t)(row0 + j) * DM + col] = acc[mt][nt][j];
        }
}

// ---- intra-chunk attention + summaries, all MFMA ----
__global__ __launch_bounds__(256) void chunk_local_mfma(
    const unsigned short* __restrict__ Qb, const unsigned short* __restrict__ Kb,
    const unsigned short* __restrict__ Vb, const float* __restrict__ logit,
    float* __restrict__ OI, float* __restrict__ DI,
    float* __restrict__ KV, float* __restrict__ KZ)
{
    const int chunk = blockIdx.x, dg = blockIdx.y, b = blockIdx.z;
    const int tid = threadIdx.x;
    const int lane = tid & 63, wid = tid >> 6;
    const int wr = wid >> 1, wc = wid & 1;
    const int lr = lane & 15, lk = lane >> 4;
    const int t0 = chunk * CHK;
    const float ld = get_ld(logit);

    __shared__ unsigned short Qs[64][72];
    __shared__ unsigned short Ks[64][72];
    __shared__ unsigned short As[64][72];
    __shared__ unsigned short Kws[64][66];
    __shared__ unsigned short Vs[64][134];
    __shared__ float wks[64];
    __shared__ float cps[64];
    __shared__ float DIsh[64];

    if (tid < 64) {
        const float c = cpos(ld, t0 + tid);
        cps[tid] = c;
        wks[tid] = expf(cpos(ld, t0 + CHK - 1) - c);
        DIsh[tid] = 0.f;
    }
    __syncthreads();

    const unsigned short* Qg = Qb + ((size_t)b * LSEQ + t0) * MM;
    const unsigned short* Kg = Kb + ((size_t)b * LSEQ + t0) * MM;
#pragma unroll
    for (int l = 0; l < 2; ++l) {
        const int e = tid + l * 256;
        const int r = e >> 3, gq = e & 7;
        *(uint4*)&Qs[r][gq * 8] = *(const uint4*)(Qg + (size_t)e * 8);
        uint4 kraw = *(const uint4*)(Kg + (size_t)e * 8);
        *(uint4*)&Ks[r][gq * 8] = kraw;
        const float w = wks[r];
        const unsigned short* kp = (const unsigned short*)&kraw;
#pragma unroll
        for (int p = 0; p < 4; ++p) {
            ushort2 o;
            o.x = f2bf(w * bf2f(kp[2 * p]));
            o.y = f2bf(w * bf2f(kp[2 * p + 1]));
            *(ushort2*)&Kws[r][gq * 8 + 2 * p] = o;
        }
    }
    const unsigned short* Vg = Vb + ((size_t)b * LSEQ + t0) * DM + dg * 128;
#pragma unroll
    for (int l = 0; l < 4; ++l) {
        const int e = tid + l * 256;
        const int s = e >> 4, gg = e & 15;
        uint4 vr = *(const uint4*)(Vg + (size_t)s * DM + gg * 8);
        const unsigned short* vp = (const unsigned short*)&vr;
#pragma unroll
        for (int p = 0; p < 4; ++p) {
            ushort2 o;
            o.x = vp[2 * p]; o.y = vp[2 * p + 1];
            *(ushort2*)&Vs[s][gg * 8 + 2 * p] = o;
        }
    }
    __syncthreads();

    f32x4 sacc[2][2];
#pragma unroll
    for (int i = 0; i < 2; ++i)
#pragma unroll
        for (int j = 0; j < 2; ++j) sacc[i][j] = (f32x4)(0.f);
#pragma unroll
    for (int ks = 0; ks < 2; ++ks) {
        short8v qa[2], kb2[2];
#pragma unroll
        for (int mt = 0; mt < 2; ++mt)
            qa[mt] = *(const short8v*)&Qs[wr * 32 + mt * 16 + lr][ks * 32 + lk * 8];
#pragma unroll
        for (int nt = 0; nt < 2; ++nt)
            kb2[nt] = *(const short8v*)&Ks[wc * 32 + nt * 16 + lr][ks * 32 + lk * 8];
#pragma unroll
        for (int mt = 0; mt < 2; ++mt)
#pragma unroll
            for (int nt = 0; nt < 2; ++nt)
                sacc[mt][nt] = __builtin_amdgcn_mfma_f32_16x16x32_bf16(
                    qa[mt], kb2[nt], sacc[mt][nt], 0, 0, 0);
    }

#pragma unroll
    for (int mt = 0; mt < 2; ++mt) {
#pragma unroll
        for (int j = 0; j < 4; ++j) {
            const int t = wr * 32 + mt * 16 + lk * 4 + j;
            const float ct = cps[t];
            float rowpart = 0.f;
#pragma unroll
            for (int nt = 0; nt < 2; ++nt) {
                const int s = wc * 32 + nt * 16 + lr;
                float v = sacc[mt][nt][j];
                v = (s <= t) ? v * expf(ct - cps[s]) : 0.f;
                rowpart += v;
                As[t][s] = f2bf(v);
            }
            rowpart += __shfl_xor(rowpart, 1);
            rowpart += __shfl_xor(rowpart, 2);
            rowpart += __shfl_xor(rowpart, 4);
            rowpart += __shfl_xor(rowpart, 8);
            if (lr == 0) atomicAdd(&DIsh[t], rowpart);
        }
    }
    __syncthreads();

    if (dg == 0) {
        if (tid < 64) DI[(size_t)b * LSEQ + t0 + tid] = DIsh[tid];
        if (tid >= 64 && tid < 128) {
            const int m = tid - 64;
            float z = 0.f;
#pragma unroll
            for (int s = 0; s < 64; ++s) z += wks[s] * bf2f(Ks[s][m]);
            KZ[((size_t)b * NCHUNK + chunk) * MM + m] = z;
        }
    }

    f32x4 aO[2][4], aK[2][4];
#pragma unroll
    for (int i = 0; i < 2; ++i)
#pragma unroll
        for (int j = 0; j < 4; ++j) { aO[i][j] = (f32x4)(0.f); aK[i][j] = (f32x4)(0.f); }

#pragma unroll
    for (int ks = 0; ks < 2; ++ks) {
        short8v vf[4];
#pragma unroll
        for (int nt = 0; nt < 4; ++nt) {
            unsigned short* vp = (unsigned short*)&vf[nt];
            const int n = wc * 64 + nt * 16 + lr;
#pragma unroll
            for (int e = 0; e < 8; ++e)
                vp[e] = Vs[ks * 32 + lk * 8 + e][n];
        }
        short8v af2[2], kf2[2];
#pragma unroll
        for (int mt = 0; mt < 2; ++mt) {
            const int row = wr * 32 + mt * 16 + lr;
            af2[mt] = *(const short8v*)&As[row][ks * 32 + lk * 8];
            unsigned short* kp = (unsigned short*)&kf2[mt];
#pragma unroll
            for (int e = 0; e < 8; ++e)
                kp[e] = Kws[ks * 32 + lk * 8 + e][row];
        }
#pragma unroll
        for (int mt = 0; mt < 2; ++mt)
#pragma unroll
            for (int nt = 0; nt < 4; ++nt) {
                aO[mt][nt] = __builtin_amdgcn_mfma_f32_16x16x32_bf16(
                    af2[mt], vf[nt], aO[mt][nt], 0, 0, 0);
                aK[mt][nt] = __builtin_amdgcn_mfma_f32_16x16x32_bf16(
                    kf2[mt], vf[nt], aK[mt][nt], 0, 0, 0);
            }
    }

    float* OIb = OI + ((size_t)b * LSEQ + t0) * DM + dg * 128;
    float* KVb = KV + ((size_t)b * NCHUNK + chunk) * MM * DM + dg * 128;
#pragma unroll
    for (int mt = 0; mt < 2; ++mt)
#pragma unroll
        for (int nt = 0; nt < 4; ++nt) {
            const int col = wc * 64 + nt * 16 + lr;
#pragma unroll
            for (int j = 0; j < 4; ++j) {
                const int row = wr * 32 + mt * 16 + lk * 4 + j;
                OIb[(size_t)row * DM + col] = aO[mt][nt][j];
                KVb[(size_t)row * DM + col] = aK[mt][nt][j];
            }
        }
}

// ---- sequential scan over chunks; S_prev emitted bf16 ----
__global__ __launch_bounds__(256) void state_scan(
    const float* __restrict__ KV, const float* __restrict__ KZ,
    const float* __restrict__ logit,
    unsigned short* __restrict__ SS, float* __restrict__ ZS)
{
    const int g = blockIdx.x * 256 + threadIdx.x;
    const int b = g >> 15;
    const int rem = g & 32767;
    const int m = rem >> 9;
    const int d = rem & 511;
    const float ld = get_ld(logit);
    const size_t base = (((size_t)b * NCHUNK) * MM + m) * DM + d;
    const size_t cstride = (size_t)MM * DM;

    float v[NCHUNK];
#pragma unroll
    for (int i = 0; i < NCHUNK; ++i) v[i] = KV[base + (size_t)i * cstride];

    float s = 0.f, cprev = 0.f;
#pragma unroll
    for (int i = 0; i < NCHUNK; ++i) {
        const float ce = cpos(ld, i * CHK + CHK - 1);
        const float lam = expf(ce - cprev);
        cprev = ce;
        SS[base + (size_t)i * cstride] = f2bf(s);
        s = lam * s + v[i];
    }
    if (d == 0) {
        float zs = 0.f;
        cprev = 0.f;
#pragma unroll
        for (int i = 0; i < NCHUNK; ++i) {
            const float ce = cpos(ld, i * CHK + CHK - 1);
            const float lam = expf(ce - cprev);
            cprev = ce;
            const int zi = (b * NCHUNK + i) * MM + m;
            ZS[zi] = zs;
            zs = lam * zs + KZ[zi];
        }
    }
}

// ---- fused inter-chunk combine + DEN + RMS norm -> bf16 NRM ----
__global__ __launch_bounds__(256) void combine_rms(
    const unsigned short* __restrict__ Qb, const unsigned short* __restrict__ SSb,
    const float* __restrict__ ZS, const float* __restrict__ OI,
    const float* __restrict__ DI, const float* __restrict__ logit,
    const float* __restrict__ norm_w, unsigned short* __restrict__ NRM)
{
    const int chunk = blockIdx.x, b = blockIdx.y;
    const int tid = threadIdx.x;
    const int lane = tid & 63, w = tid >> 6;   // wave -> col block w*128
    const int lr = lane & 15, lk = lane >> 4;
    const int t0 = chunk * CHK;
    const float ld = get_ld(logit);

    __shared__ unsigned short Qs[64][72];
    __shared__ unsigned short Ssh[64][514];   // pad 514: strided u16 reads conflict-free
    __shared__ float wsh[512];
    __shared__ float gv[64], invden[64], xsq[64], rinv_s[64];

    // stage Q (64x64 bf16)
    {
        const unsigned short* Qg = Qb + ((size_t)b * LSEQ + t0) * MM;
#pragma unroll
        for (int l = 0; l < 2; ++l) {
            const int e = tid + l * 256;
            const int r = e >> 3, g8 = e & 7;
            *(uint4*)&Qs[r][g8 * 8] = *(const uint4*)(Qg + (size_t)e * 8);
        }
    }
    // stage S_prev (64x512 bf16), row pad 514
    {
        const unsigned short* Sg = SSb + ((size_t)(b * NCHUNK + chunk) * MM) * DM;
#pragma unroll
        for (int l = 0; l < 16; ++l) {
            const int e = tid + l * 256;
            const int m = e >> 6, g8 = e & 63;
            uint4 v = *(const uint4*)(Sg + (size_t)m * DM + g8 * 8);
            const unsigned short* vp = (const unsigned short*)&v;
#pragma unroll
            for (int p = 0; p < 4; ++p) {
                ushort2 o; o.x = vp[2 * p]; o.y = vp[2 * p + 1];
                *(ushort2*)&Ssh[m][g8 * 8 + 2 * p] = o;
            }
        }
    }
    wsh[tid] = norm_w[tid];
    wsh[tid + 256] = norm_w[tid + 256];
    if (tid < 64) {
        const float cprev = (chunk > 0) ? cpos(ld, t0 - 1) : 0.f;
        gv[tid] = expf(cpos(ld, t0 + tid) - cprev);
        xsq[tid] = 0.f;
    }
    __syncthreads();

    // DEN (threads 0..63)
    if (tid < 64) {
        const float* zp = ZS + ((size_t)b * NCHUNK + chunk) * MM;
        float a = 0.f;
#pragma unroll
        for (int m = 0; m < MM; ++m) a += bf2f(Qs[tid][m]) * zp[m];
        invden[tid] = 1.0f / (gv[tid] * a + DI[(size_t)b * LSEQ + t0 + tid] + 1e-6f);
    }

    // O_inter = Q @ S_prev : each wave does all 64 rows x 128 cols
    f32x4 acc[4][8];
#pragma unroll
    for (int i = 0; i < 4; ++i)
#pragma unroll
        for (int j = 0; j < 8; ++j) acc[i][j] = (f32x4)(0.f);

#pragma unroll
    for (int ks = 0; ks < 2; ++ks) {
        short8v vf[8];
#pragma unroll
        for (int nt = 0; nt < 8; ++nt) {
            unsigned short* vp = (unsigned short*)&vf[nt];
            const int col = w * 128 + nt * 16 + lr;
#pragma unroll
            for (int e = 0; e < 8; ++e)
                vp[e] = Ssh[ks * 32 + lk * 8 + e][col];
        }
        short8v af[4];
#pragma unroll
        for (int mt = 0; mt < 4; ++mt)
            af[mt] = *(const short8v*)&Qs[mt * 16 + lr][ks * 32 + lk * 8];
#pragma unroll
        for (int mt = 0; mt < 4; ++mt)
#pragma unroll
            for (int nt = 0; nt < 8; ++nt)
                acc[mt][nt] = __builtin_amdgcn_mfma_f32_16x16x32_bf16(
                    af[mt], vf[nt], acc[mt][nt], 0, 0, 0);
    }
    __syncthreads();   // invden visible

    // x = (gv*acc + OI)/den ; accumulate row sums of x^2
    const float* OIb = OI + ((size_t)b * LSEQ + t0) * DM;
#pragma unroll
    for (int mt = 0; mt < 4; ++mt) {
#pragma unroll
        for (int j = 0; j < 4; ++j) {
            const int row = mt * 16 + lk * 4 + j;
            const float g = gv[row];
            const float inv = invden[row];
            float part = 0.f;
#pragma unroll
            for (int nt = 0; nt < 8; ++nt) {
                const int col = w * 128 + nt * 16 + lr;
                float v = g * acc[mt][nt][j] + OIb[(size_t)row * DM + col];
                float xx = v * inv;
                acc[mt][nt][j] = xx;
                part += xx * xx;
            }
            part += __shfl_xor(part, 1);
            part += __shfl_xor(part, 2);
            part += __shfl_xor(part, 4);
            part += __shfl_xor(part, 8);
            if (lr == 0) atomicAdd(&xsq[row], part);
        }
    }
    __syncthreads();
    if (tid < 64)
        rinv_s[tid] = 1.0f / sqrtf(xsq[tid] * (1.0f / (float)DM) + 1e-6f);
    __syncthreads();

    unsigned short* NRMb = NRM + ((size_t)b * LSEQ + t0) * DM;
#pragma unroll
    for (int mt = 0; mt < 4; ++mt)
#pragma unroll
        for (int j = 0; j < 4; ++j) {
            const int row = mt * 16 + lk * 4 + j;
            const float r = rinv_s[row];
#pragma unroll
            for (int nt = 0; nt < 8; ++nt) {
                const int col = w * 128 + nt * 16 + lr;
                NRMb[(size_t)row * DM + col] = f2bf(acc[mt][nt][j] * r * wsh[col]);
            }
        }
}

extern "C" void kernel_launch(void* const* d_in, const int* in_sizes, int n_in,
                              void* d_out, int out_size, void* d_ws, size_t ws_size,
                              hipStream_t stream) {
    const float* x      = (const float*)d_in[0];
    const float* W_q    = (const float*)d_in[1];
    const float* W_k    = (const float*)d_in[2];
    const float* W_v    = (const float*)d_in[3];
    const float* W_o    = (const float*)d_in[4];
    const float* logit  = (const float*)d_in[5];
    const float* norm_w = (const float*)d_in[6];
    float* out = (float*)d_out;

    const size_t BLM = (size_t)NB * LSEQ * MM;          // 262144
    const size_t BLD = (size_t)NB * LSEQ * DM;          // 2097152
    const size_t BL  = (size_t)NB * LSEQ;               // 4096
    const size_t BNCMD = (size_t)NB * NCHUNK * MM * DM; // 2097152
    const size_t BNCM  = (size_t)NB * NCHUNK * MM;      // 4096
    const size_t WSZ = (size_t)DM * DM;                 // 262144
    const size_t WQK = (size_t)MM * DM;                 // 32768

    float* ws = (float*)d_ws;
    float* OIp  = ws;
    float* DIp  = OIp + BLD;
    float* KVp  = DIp + BL;
    float* KZp  = KVp + BNCMD;
    float* ZSp  = KZp + BNCM;
    unsigned short* Xb   = (unsigned short*)(ZSp + BNCM);
    unsigned short* Wvb  = Xb + BLD;
    unsigned short* Wob  = Wvb + WSZ;
    unsigned short* Wqb  = Wob + WSZ;
    unsigned short* Wkb  = Wqb + WQK;
    unsigned short* Qb16 = Wkb + WQK;
    unsigned short* Kb16 = Qb16 + BLM;
    unsigned short* Vb16 = Kb16 + BLM;
    unsigned short* SSb  = Vb16 + BLD;
    unsigned short* NRMb = SSb + BNCMD;

    // 1. bf16 conversions
    cvt_all<<<dim3(2624), 256, 0, stream>>>(x, W_v, W_o, W_q, W_k,
                                            Xb, Wvb, Wob, Wqb, Wkb);
    // 2. fused Q|K|V projection
    gemm_proj<<<dim3(32, 5), 256, 0, stream>>>(Xb, Wqb, Wkb, Wvb,
                                               Qb16, Kb16, Vb16);
    // 3. intra-chunk attention + summaries
    chunk_local_mfma<<<dim3(NCHUNK, 4, NB), 256, 0, stream>>>(
        Qb16, Kb16, Vb16, logit, OIp, DIp, KVp, KZp);
    // 4. sequential state scan
    state_scan<<<dim3(256), 256, 0, stream>>>(KVp, KZp, logit, SSb, ZSp);
    // 5. combine + DEN + RMS -> bf16
    combine_rms<<<dim3(NCHUNK, NB), 256, 0, stream>>>(
        Qb16, SSb, ZSp, OIp, DIp, logit, norm_w, NRMb);
    // 6. output projection
    gemm_out<<<dim3(32, 4), 256, 0, stream>>>(NRMb, Wob, out);
}